// Round 9
// baseline (510.370 us; speedup 1.0000x reference)
//
#include <hip/hip_runtime.h>
#include <hip/hip_bf16.h>
#include <math.h>

#define BSZ 4
#define VN 2048
#define SS 7
#define KNB 10

typedef __attribute__((ext_vector_type(8))) short short8;
typedef __attribute__((ext_vector_type(4))) float f32x4;
typedef __attribute__((address_space(1))) const void gcvoid;
typedef __attribute__((address_space(3))) void lvoid;

__device__ inline ushort f2bf(float x) {
    __hip_bfloat16 h = __float2bfloat16(x);
    return *(ushort*)&h;
}

// async global->LDS 16B per lane (dest must be wave-uniform base + lane*16)
__device__ inline void gl2lds16(const ushort* g, ushort* l) {
    __builtin_amdgcn_global_load_lds((gcvoid*)g, (lvoid*)l, 16, 0, 0);
}

// monotonic float<->uint encoding for atomicMax on floats
__device__ inline unsigned fenc(float f) {
    unsigned b = __float_as_uint(f);
    return (b & 0x80000000u) ? ~b : (b | 0x80000000u);
}
__device__ inline float fdec(unsigned e) {
    unsigned b = (e & 0x80000000u) ? (e & 0x7FFFFFFFu) : ~e;
    return __uint_as_float(b);
}

#define INS(dq, iq, dd, jj) { bool lt_ = (dd) < (dq); \
    float dmn_ = lt_ ? (dd) : (dq); float dmx_ = lt_ ? (dq) : (dd); \
    int imn_ = lt_ ? (jj) : (iq); int imx_ = lt_ ? (iq) : (jj); \
    (dq) = dmn_; (iq) = imn_; (dd) = dmx_; (jj) = imx_; }

// ---------------------------------------------------------------- prep uber
#define PB0 8960L
#define PB1 24320L
#define PB2 958208L
#define PB3 1220352L

__global__ void prep_uber(const float* __restrict__ d0, const float* __restrict__ d1,
                          const float* __restrict__ d2, const float* __restrict__ d3,
                          const float* __restrict__ d4,
                          float* __restrict__ s0, float* __restrict__ s1,
                          float* __restrict__ s2, float* __restrict__ s3, float* __restrict__ s4,
                          const float* __restrict__ wc3, float* __restrict__ wc3t,
                          const float* __restrict__ wc1, ushort* __restrict__ wc1b,
                          const float* __restrict__ wc2, ushort* __restrict__ wc2b) {
    long i = blockIdx.x * 256L + threadIdx.x;
    if (i < PB0) {
        const float* src; float* dst; int C, c;
        if (i < 896)        { src = d0; dst = s0; C = 896;  c = (int)i; }
        else if (i < 1792)  { src = d1; dst = s1; C = 896;  c = (int)i - 896; }
        else if (i < 3584)  { src = d2; dst = s2; C = 1792; c = (int)i - 1792; }
        else if (i < 5376)  { src = d3; dst = s3; C = 1792; c = (int)i - 3584; }
        else                { src = d4; dst = s4; C = 3584; c = (int)i - 5376; }
        float a = src[c], b = src[C + c], e = src[2 * C + c];
        float den = fmaxf(sqrtf(a * a + b * b + e * e), 1e-12f);
        dst[c] = a / den; dst[C + c] = b / den; dst[2 * C + c] = e / den;
    } else if (i < PB1) {
        long j = i - PB0;
        int o = (int)(j / 512), k = (int)(j % 512);
        wc3t[(long)k * 30 + o] = wc3[j];
    } else if (i < PB2) {
        long j = i - PB1;
        int c = (int)(j % 1824);
        long r = j / 1824;
        wc1b[j] = f2bf(c < 1808 ? wc1[r * 1808 + c] : 0.f);
    } else if (i < PB3) {
        long j = i - PB2;
        wc2b[j] = f2bf(wc2[j]);
    }
}

// ---------------------------------------------------------------- layer weights tiled transpose
__global__ __launch_bounds__(256) void wt_trans_all(const float* __restrict__ w1, const float* __restrict__ w2,
                                                    const float* __restrict__ w3, const float* __restrict__ w4,
                                                    ushort* __restrict__ o1, ushort* __restrict__ o2,
                                                    ushort* __restrict__ o3, ushort* __restrict__ o4) {
    __shared__ float tile[32][33];
    int gb = blockIdx.x;
    const float* w; ushort* o; int K, N, t;
    if (gb < 128)      { w = w1; o = o1; K = 128; N = 1024; t = gb; }
    else if (gb < 384) { w = w2; o = o2; K = 128; N = 2048; t = gb - 128; }
    else if (gb < 896) { w = w3; o = o3; K = 256; N = 2048; t = gb - 384; }
    else               { w = w4; o = o4; K = 256; N = 4096; t = gb - 896; }
    int tn = t % (N / 32), tk = t / (N / 32);
    int n0 = tn * 32, k0 = tk * 32;
    int tx = threadIdx.x % 32, ty = threadIdx.x / 32;
#pragma unroll
    for (int r = 0; r < 32; r += 8)
        tile[ty + r][tx] = w[(long)(k0 + ty + r) * N + n0 + tx];
    __syncthreads();
#pragma unroll
    for (int r = 0; r < 32; r += 8)
        o[(long)(n0 + ty + r) * K + k0 + tx] = f2bf(tile[tx][ty + r]);
}

// ---------------------------------------------------------------- knn uber
// per-chunk dual top-K lists over even/odd 64-halves (ILP); merge sees 2*nch chunks
#define KOFF0 0L
#define KOFF1 2621440L
#define KOFF2 2785280L
#define KOFF3 2795520L
#define KOFF4 3057664L
#define KTOT  3074048L

template <int KK>
__device__ void knn_part_dev(const float* __restrict__ verts, int Nsrc, int T, int nch,
                             int tile, int b, int ch,
                             float* __restrict__ pd, int* __restrict__ pi,
                             float4* __restrict__ s4) {
    const float* vb = verts + (long)b * VN * 3;
    int j0 = ch * 128;
    for (int j = threadIdx.x; j < 128; j += 256) {
        float x = vb[(j0 + j) * 3 + 0];
        float y = vb[(j0 + j) * 3 + 1];
        float z = vb[(j0 + j) * 3 + 2];
        s4[j] = make_float4(x, y, z, x * x + y * y + z * z);
    }
    __syncthreads();
    int i = tile * 256 + threadIdx.x;
    if (i >= T) return;
    float px = vb[i * 3], py = vb[i * 3 + 1], pz = vb[i * 3 + 2];
    float d0[KK], d1[KK]; int id0[KK], id1[KK];
#pragma unroll
    for (int q = 0; q < KK; q++) { d0[q] = 1e30f; id0[q] = 0; d1[q] = 1e30f; id1[q] = 0; }
    for (int j = 0; j < 64; j++) {
        float4 sA = s4[j];
        float4 sB = s4[64 + j];
        float dA = fmaf(-2.f, px * sA.x + py * sA.y + pz * sA.z, sA.w);
        float dB = fmaf(-2.f, px * sB.x + py * sB.y + pz * sB.z, sB.w);
        int jA = j0 + j, jB = j0 + 64 + j;
        dA = (jA == i) ? 1e30f : dA;
        dB = (jB == i) ? 1e30f : dB;
#pragma unroll
        for (int q = 0; q < KK; q++) { INS(d0[q], id0[q], dA, jA); }
#pragma unroll
        for (int q = 0; q < KK; q++) { INS(d1[q], id1[q], dB, jB); }
    }
    long base = (((long)b * T + i) * nch * 2 + 2 * ch) * KK;
#pragma unroll
    for (int q = 0; q < KK; q++) { pd[base + q] = d0[q]; pi[base + q] = id0[q]; }
#pragma unroll
    for (int q = 0; q < KK; q++) { pd[base + KK + q] = d1[q]; pi[base + KK + q] = id1[q]; }
}

__device__ void nearest_dev(const float* __restrict__ verts, int SN, int* __restrict__ out,
                            int gl, float4* __restrict__ s4) {
    int t = gl * 256 + threadIdx.x;
    int b = t / VN;
    const float* vb = verts + (long)b * VN * 3;
    for (int j = threadIdx.x; j < SN; j += 256) {
        float x = vb[j * 3], y = vb[j * 3 + 1], z = vb[j * 3 + 2];
        s4[j] = make_float4(x, y, z, x * x + y * y + z * z);
    }
    __syncthreads();
    int i = t % VN;
    float px = vb[i * 3], py = vb[i * 3 + 1], pz = vb[i * 3 + 2];
    int h = SN / 2;
    float b0 = 1e30f, b1 = 1e30f; int i0 = 0, i1 = 0;
    for (int j = 0; j < h; j++) {
        float4 sA = s4[j];
        float4 sB = s4[h + j];
        float dA = fmaf(-2.f, px * sA.x + py * sA.y + pz * sA.z, sA.w);
        float dB = fmaf(-2.f, px * sB.x + py * sB.y + pz * sB.z, sB.w);
        bool lA = dA < b0; b0 = lA ? dA : b0; i0 = lA ? j : i0;
        bool lB = dB < b1; b1 = lB ? dB : b1; i1 = lB ? (h + j) : i1;
    }
    out[t] = (b1 < b0) ? i1 : i0;   // strict <: lower-index half wins ties
}

__global__ __launch_bounds__(256) void knn_part_uber(const float* __restrict__ verts,
                                                     float* __restrict__ pd, int* __restrict__ pi,
                                                     int* __restrict__ n1, int* __restrict__ n2) {
    __shared__ float4 smem[512];
    int gb = blockIdx.x;
    if (gb < 512) {
        int tile = gb % 8, bc = gb / 8;
        knn_part_dev<10>(verts, 2048, 2048, 16, tile, bc / 16, bc % 16, pd + KOFF0, pi + KOFF0, smem);
    } else if (gb < 544) {
        int local = gb - 512, tile = local % 2, bc = local / 2;
        knn_part_dev<10>(verts, 512, 512, 4, tile, bc / 4, bc % 4, pd + KOFF1, pi + KOFF1, smem);
    } else if (gb < 548) {
        int bc = gb - 544;
        knn_part_dev<10>(verts, 128, 128, 1, 0, bc, 0, pd + KOFF2, pi + KOFF2, smem);
    } else if (gb < 676) {
        int local = gb - 548, tile = local % 2, bc = local / 2;
        knn_part_dev<4>(verts, 2048, 512, 16, tile, bc / 16, bc % 16, pd + KOFF3, pi + KOFF3, smem);
    } else if (gb < 692) {
        int bc = gb - 676;
        knn_part_dev<4>(verts, 512, 128, 4, 0, bc / 4, bc % 4, pd + KOFF4, pi + KOFF4, smem);
    } else if (gb < 724) {
        nearest_dev(verts, 512, n1, gb - 692, smem);
    } else {
        nearest_dev(verts, 128, n2, gb - 724, smem);
    }
}

template <int KK, int NCH>
__device__ void knn_merge_dev(const float* __restrict__ pd, const int* __restrict__ pi,
                              int t, int* __restrict__ out) {
    float d[KK]; int id[KK];
#pragma unroll
    for (int q = 0; q < KK; q++) { d[q] = 1e30f; id[q] = 0; }
    for (int c = 0; c < NCH; c++) {
        long base = ((long)t * NCH + c) * KK;
        for (int q = 0; q < KK; q++) {
            float dd = pd[base + q];
            if (dd >= d[KK - 1]) break;
            int jj = pi[base + q];
#pragma unroll
            for (int p = 0; p < KK; p++) { INS(d[p], id[p], dd, jj); }
        }
    }
#pragma unroll
    for (int q = 0; q < KK; q++) out[(long)t * KK + q] = id[q];
}

__global__ void knn_merge_uber(const float* __restrict__ pd, const int* __restrict__ pi,
                               int* __restrict__ nb, int* __restrict__ nb1, int* __restrict__ nb2,
                               int* __restrict__ nbp1, int* __restrict__ nbp2) {
    int gt = blockIdx.x * 256 + threadIdx.x;
    if (gt < 8192)       knn_merge_dev<10, 32>(pd + KOFF0, pi + KOFF0, gt, nb);
    else if (gt < 10240) knn_merge_dev<10, 8>(pd + KOFF1, pi + KOFF1, gt - 8192, nb1);
    else if (gt < 10752) knn_merge_dev<10, 2>(pd + KOFF2, pi + KOFF2, gt - 10240, nb2);
    else if (gt < 12800) knn_merge_dev<4, 32>(pd + KOFF3, pi + KOFF3, gt - 10752, nbp1);
    else                 knn_merge_dev<4, 8>(pd + KOFF4, pi + KOFF4, gt - 12800, nbp2);
}

// ---------------------------------------------------------------- conv_surface (fp32 + bf16 out)
__global__ void conv_surface_kernel(const float* __restrict__ verts, const int* __restrict__ nb,
                                    const float* __restrict__ sd, float* __restrict__ fm0,
                                    ushort* __restrict__ fm0b) {
    int bv = blockIdx.x;
    int b = bv / VN, v = bv % VN;
    __shared__ float snd[KNB][3];
    int tid = threadIdx.x;
    if (tid < KNB) {
        int nj = nb[(long)bv * KNB + tid];
        const float* vb = verts + (long)b * VN * 3;
        float dx = vb[nj * 3] - vb[v * 3];
        float dy = vb[nj * 3 + 1] - vb[v * 3 + 1];
        float dz = vb[nj * 3 + 2] - vb[v * 3 + 2];
        float den = fmaxf(sqrtf(dx * dx + dy * dy + dz * dz), 1e-12f);
        snd[tid][0] = dx / den; snd[tid][1] = dy / den; snd[tid][2] = dz / den;
    }
    __syncthreads();
    int c = tid;
    float acc = 0.f;
    for (int s = 0; s < SS; s++) {
        int col = s * 128 + c;
        float s0 = sd[col], s1 = sd[896 + col], s2 = sd[2 * 896 + col];
        float m = 0.f;
#pragma unroll
        for (int n = 0; n < KNB; n++) {
            float dot = snd[n][0] * s0 + snd[n][1] * s1 + snd[n][2] * s2;
            m = fmaxf(m, dot);
        }
        acc += m;
    }
    fm0[(long)bv * 128 + c] = acc;
    fm0b[(long)bv * 128 + c] = f2bf(acc);
}

// ---------------------------------------------------------------- conv_layer act (+opt fg max)
__global__ void conv_act_kernel(const float* __restrict__ verts, const int* __restrict__ nb,
                                const float* __restrict__ sd, const float* __restrict__ fo,
                                float* __restrict__ out, unsigned* __restrict__ fgmax,
                                int Vl, int outC) {
    int bv = blockIdx.x;
    int b = bv / Vl, v = bv % Vl;
    __shared__ float snd[KNB][3];
    __shared__ int srow[KNB];
    int tid = threadIdx.x;
    if (tid < KNB) {
        int nj = nb[(long)bv * KNB + tid];
        srow[tid] = b * Vl + nj;
        const float* vb = verts + (long)b * VN * 3;
        float dx = vb[nj * 3] - vb[v * 3];
        float dy = vb[nj * 3 + 1] - vb[v * 3 + 1];
        float dz = vb[nj * 3 + 2] - vb[v * 3 + 2];
        float den = fmaxf(sqrtf(dx * dx + dy * dy + dz * dz), 1e-12f);
        snd[tid][0] = dx / den; snd[tid][1] = dy / den; snd[tid][2] = dz / den;
    }
    __syncthreads();
    int c = tid;
    int SC = SS * outC;
    int foN = SC + outC;
    float acc = fo[(long)bv * foN + c];
    for (int s = 0; s < SS; s++) {
        int col = s * outC + c;
        float s0 = sd[col], s1 = sd[SC + col], s2 = sd[2 * SC + col];
        float m = -1e30f;
#pragma unroll
        for (int n = 0; n < KNB; n++) {
            float dot = snd[n][0] * s0 + snd[n][1] * s1 + snd[n][2] * s2;
            float th = fmaxf(dot, 0.f);
            float sup = fo[(long)srow[n] * foN + outC + col];
            m = fmaxf(m, th * sup);
        }
        acc += m;
    }
    out[(long)bv * outC + c] = acc;
    if (fgmax) atomicMax(&fgmax[b * outC + c], fenc(acc));
}

// ---------------------------------------------------------------- batchnorm stats
__global__ __launch_bounds__(256) void bn_stat_kernel(const float* __restrict__ x,
                                                      float* __restrict__ stat, int R, int C) {
    int rp = 256 / C;
    int c = threadIdx.x % C;
    int rs = threadIdx.x / C;
    float s = 0.f, s2 = 0.f;
    for (long r = (long)blockIdx.x * rp + rs; r < R; r += (long)gridDim.x * rp) {
        float v = x[r * C + c];
        s += v; s2 += v * v;
    }
    atomicAdd(&stat[c], s);
    atomicAdd(&stat[C + c], s2);
}

__global__ void bn_apply_relu_kernel(const float* __restrict__ x, const float* __restrict__ stat,
                                     const float* __restrict__ g, const float* __restrict__ be,
                                     float* __restrict__ out, ushort* __restrict__ outb, int R, int C) {
    long i = blockIdx.x * 256L + threadIdx.x;
    if (i >= (long)R * C) return;
    int c = (int)(i % C);
    float mu = stat[c] / R;
    float var = stat[C + c] / R - mu * mu;
    var = fmaxf(var, 0.f);
    float y = (x[i] - mu) * rsqrtf(var + 1e-5f) * g[c] + be[c];
    y = fmaxf(y, 0.f);
    out[i] = y;
    if (outb) outb[i] = f2bf(y);
}

// ---------------------------------------------------------------- pool -> bf16
__global__ void pool_b_kernel(const float* __restrict__ fm, const int* __restrict__ idx,
                              ushort* __restrict__ out, int Vin, int T, int C) {
    long i = blockIdx.x * 256L + threadIdx.x;
    if (i >= (long)BSZ * T * C) return;
    int c = (int)(i % C);
    long bt = i / C;
    int b = (int)(bt / T), t = (int)(bt % T);
    const int* id = idx + ((long)b * T + t) * 4;
    float m = -1e30f;
#pragma unroll
    for (int n = 0; n < 4; n++)
        m = fmaxf(m, fm[((long)b * Vin + id[n]) * C + c]);
    out[i] = f2bf(m);
}

// ---------------------------------------------------------------- bf16 MFMA GEMM, 128x128 tile (async LDS)
__global__ __launch_bounds__(256) void gemm_mfma_bt_kernel(
    const ushort* __restrict__ A, const ushort* __restrict__ Bt,
    const float* __restrict__ bias, float* __restrict__ Cf, ushort* __restrict__ Cb,
    int M, int N, int K, int relu)
{
    __shared__ ushort As[128 * 32];
    __shared__ ushort Bs[128 * 32];
    int t = threadIdx.x;
    int w = t >> 6, l = t & 63;
    int quad = l >> 4, lm = l & 15;
    int wm = w >> 1, wn = w & 1;
    long m0 = blockIdx.y * 128L;
    long n0 = blockIdx.x * 128L;
    int lr = t >> 2;
    int lk = (t & 3) * 8;
    f32x4 acc[4][4];
#pragma unroll
    for (int i = 0; i < 4; i++)
#pragma unroll
        for (int j = 0; j < 4; j++) acc[i][j] = (f32x4){0.f, 0.f, 0.f, 0.f};

    for (int k0 = 0; k0 < K; k0 += 32) {
        __syncthreads();
        gl2lds16(A + (m0 + lr) * K + k0 + lk, &As[lr * 32 + lk]);
        gl2lds16(A + (m0 + 64 + lr) * K + k0 + lk, &As[(64 + lr) * 32 + lk]);
        gl2lds16(Bt + (n0 + lr) * K + k0 + lk, &Bs[lr * 32 + lk]);
        gl2lds16(Bt + (n0 + 64 + lr) * K + k0 + lk, &Bs[(64 + lr) * 32 + lk]);
        __syncthreads();
        short8 af[4], bfr[4];
#pragma unroll
        for (int i = 0; i < 4; i++)
            af[i] = *(const short8*)&As[(wm * 64 + i * 16 + lm) * 32 + quad * 8];
#pragma unroll
        for (int j = 0; j < 4; j++)
            bfr[j] = *(const short8*)&Bs[(wn * 64 + j * 16 + lm) * 32 + quad * 8];
#pragma unroll
        for (int i = 0; i < 4; i++)
#pragma unroll
            for (int j = 0; j < 4; j++)
                acc[i][j] = __builtin_amdgcn_mfma_f32_16x16x32_bf16(af[i], bfr[j], acc[i][j], 0, 0, 0);
    }
#pragma unroll
    for (int i = 0; i < 4; i++) {
#pragma unroll
        for (int j = 0; j < 4; j++) {
            int n = (int)n0 + wn * 64 + j * 16 + lm;
            float bv = bias[n];
#pragma unroll
            for (int r = 0; r < 4; r++) {
                int m = (int)m0 + wm * 64 + i * 16 + quad * 4 + r;
                float v = acc[i][j][r] + bv;
                if (relu) v = fmaxf(v, 0.f);
                if (Cf) Cf[(long)m * N + n] = v;
                if (Cb) Cb[(long)m * N + n] = f2bf(v);
            }
        }
    }
}

// ---------------------------------------------------------------- bf16 MFMA GEMM, 64x128 tile (async LDS)
__global__ __launch_bounds__(256) void gemm_mfma_bt64_kernel(
    const ushort* __restrict__ A, const ushort* __restrict__ Bt,
    const float* __restrict__ bias, float* __restrict__ Cf, ushort* __restrict__ Cb,
    int M, int N, int K, int relu)
{
    __shared__ ushort As[64 * 32];
    __shared__ ushort Bs[128 * 32];
    int t = threadIdx.x;
    int w = t >> 6, l = t & 63;
    int quad = l >> 4, lm = l & 15;
    int wm = w >> 1, wn = w & 1;
    long m0 = blockIdx.y * 64L;
    long n0 = blockIdx.x * 128L;
    int lr = t >> 2;
    int lk = (t & 3) * 8;
    f32x4 acc[2][4];
#pragma unroll
    for (int i = 0; i < 2; i++)
#pragma unroll
        for (int j = 0; j < 4; j++) acc[i][j] = (f32x4){0.f, 0.f, 0.f, 0.f};

    for (int k0 = 0; k0 < K; k0 += 32) {
        __syncthreads();
        gl2lds16(A + (m0 + lr) * K + k0 + lk, &As[lr * 32 + lk]);
        gl2lds16(Bt + (n0 + lr) * K + k0 + lk, &Bs[lr * 32 + lk]);
        gl2lds16(Bt + (n0 + 64 + lr) * K + k0 + lk, &Bs[(64 + lr) * 32 + lk]);
        __syncthreads();
        short8 af[2], bfr[4];
#pragma unroll
        for (int i = 0; i < 2; i++)
            af[i] = *(const short8*)&As[(wm * 32 + i * 16 + lm) * 32 + quad * 8];
#pragma unroll
        for (int j = 0; j < 4; j++)
            bfr[j] = *(const short8*)&Bs[(wn * 64 + j * 16 + lm) * 32 + quad * 8];
#pragma unroll
        for (int i = 0; i < 2; i++)
#pragma unroll
            for (int j = 0; j < 4; j++)
                acc[i][j] = __builtin_amdgcn_mfma_f32_16x16x32_bf16(af[i], bfr[j], acc[i][j], 0, 0, 0);
    }
#pragma unroll
    for (int i = 0; i < 2; i++) {
#pragma unroll
        for (int j = 0; j < 4; j++) {
            int n = (int)n0 + wn * 64 + j * 16 + lm;
            float bv = bias[n];
#pragma unroll
            for (int r = 0; r < 4; r++) {
                int m = (int)m0 + wm * 32 + i * 16 + quad * 4 + r;
                float v = acc[i][j][r] + bv;
                if (relu) v = fmaxf(v, 0.f);
                if (Cf) Cf[(long)m * N + n] = v;
                if (Cb) Cb[(long)m * N + n] = f2bf(v);
            }
        }
    }
}

// ---------------------------------------------------------------- wc3 head
__global__ __launch_bounds__(256) void wc3_kernel(const float* __restrict__ h2,
                                                  const float* __restrict__ wc3t,
                                                  const float* __restrict__ bc3,
                                                  float* __restrict__ out) {
    int r8 = threadIdx.x >> 5;
    int c = threadIdx.x & 31;
    long row = blockIdx.x * 8L + r8;
    const float* hr = h2 + row * 512;
    float acc = 0.f;
    if (c < 30) {
        for (int k = 0; k < 512; k++)
            acc += hr[k] * wc3t[k * 30 + c];
        acc += bc3[c];
        if (c < 6) out[row * 6 + c] = acc;
        else       out[49152 + row * 24 + (c - 6)] = acc;
    }
}

// ---------------------------------------------------------------- fuse (row-per-block)
__global__ __launch_bounds__(256) void fuse_bf_kernel(
    const float* __restrict__ fm0, const float* __restrict__ fm1,
    const float* __restrict__ fm2, const float* __restrict__ fm3,
    const float* __restrict__ fm4, const unsigned* __restrict__ fg_enc,
    const float* __restrict__ onehot,
    const int* __restrict__ n1, const int* __restrict__ n2,
    ushort* __restrict__ fuse_b, float* __restrict__ feat) {
    long row = blockIdx.x;            // 0..8191
    int b = (int)(row >> 11);
    int i1 = n1[row], i2 = n2[row];
    const float* p0 = fm0 + row * 128;
    const float* p1 = fm1 + row * 128;
    const float* p2 = fm2 + ((long)b * 512 + i1) * 256;
    const float* p3 = fm3 + ((long)b * 512 + i1) * 256;
    const float* p4 = fm4 + ((long)b * 128 + i2) * 512;
    const unsigned* pg = fg_enc + b * 512;
    const float* po = onehot + b * 16;
    ushort* fb = fuse_b + row * 1824;
    float* ft = feat + row * 1296;
#pragma unroll
    for (int k = 0; k < 8; k++) {
        int c = threadIdx.x + k * 256;
        if (c >= 1824) break;
        float val = 0.f;
        if (c < 128)       val = p0[c];
        else if (c < 256)  val = p1[c - 128];
        else if (c < 512)  val = p2[c - 256];
        else if (c < 768)  val = p3[c - 512];
        else if (c < 1280) val = p4[c - 768];
        else if (c < 1792) val = fdec(pg[c - 1280]);
        else if (c < 1808) val = po[c - 1792];
        fb[c] = f2bf(val);
        if (c < 1280)                   ft[c] = val;
        else if (c >= 1792 && c < 1808) ft[c - 512] = val;
    }
}

// ---------------------------------------------------------------- launch

extern "C" void kernel_launch(void* const* d_in, const int* in_sizes, int n_in,
                              void* d_out, int out_size, void* d_ws, size_t ws_size,
                              hipStream_t stream) {
    const float* verts  = (const float*)d_in[0];
    const float* onehot = (const float*)d_in[1];
    const float* dir0 = (const float*)d_in[2];
    const float* w1 = (const float*)d_in[3];
    const float* b1 = (const float*)d_in[4];
    const float* dir1 = (const float*)d_in[5];
    const float* w2 = (const float*)d_in[6];
    const float* b2 = (const float*)d_in[7];
    const float* dir2 = (const float*)d_in[8];
    const float* w3 = (const float*)d_in[9];
    const float* b3 = (const float*)d_in[10];
    const float* dir3 = (const float*)d_in[11];
    const float* w4 = (const float*)d_in[12];
    const float* b4 = (const float*)d_in[13];
    const float* dir4 = (const float*)d_in[14];
    const float* g_bn1 = (const float*)d_in[15];
    const float* be_bn1 = (const float*)d_in[16];
    const float* g_bn2 = (const float*)d_in[17];
    const float* be_bn2 = (const float*)d_in[18];
    const float* g_bn3 = (const float*)d_in[19];
    const float* be_bn3 = (const float*)d_in[20];
    const float* wc1 = (const float*)d_in[21];
    const float* bc1 = (const float*)d_in[22];
    const float* wc2 = (const float*)d_in[23];
    const float* bc2 = (const float*)d_in[24];
    const float* wc3 = (const float*)d_in[25];
    const float* bc3 = (const float*)d_in[26];
    float* outf = (float*)d_out;

    float* wsf = (float*)d_ws;
    size_t off = 0;
    auto alloc = [&](size_t n) { float* p = wsf + off; off += (n + 15) & ~(size_t)15; return p; };

    float* sd0 = alloc(3 * 896);
    float* sd1 = alloc(3 * 896);
    float* sd2 = alloc(3 * 1792);
    float* sd3 = alloc(3 * 1792);
    float* sd4 = alloc(3 * 3584);
    float* wc3t = alloc(512L * 30);
    float* fm0 = alloc(8192L * 128);
    float* fm1 = alloc(8192L * 128);
    float* c1  = alloc(8192L * 128);
    float* fm2 = alloc(2048L * 256);
    float* c2  = alloc(2048L * 256);
    float* fm3 = alloc(2048L * 256);
    float* c3  = alloc(2048L * 256);
    float* fm4 = alloc(512L * 512);
    float* statbase = alloc(3328);
    float* stat1 = statbase;
    float* stat2 = statbase + 256;
    float* stat3 = statbase + 768;
    unsigned* fg_enc = (unsigned*)(statbase + 1280);
    float* fbuf = alloc(8192L * 1024);
    float* h2 = alloc(8192L * 512);
    float* pd  = alloc(KTOT);
    int* pi    = (int*)alloc(KTOT);
    int* nb   = (int*)alloc(8192L * KNB);
    int* nb1  = (int*)alloc(2048L * KNB);
    int* nb2  = (int*)alloc(512L * KNB);
    int* nbp1 = (int*)alloc(2048L * 4);
    int* nbp2 = (int*)alloc(512L * 4);
    int* n1   = (int*)alloc(8192);
    int* n2   = (int*)alloc(8192);
    ushort* fuse_b = (ushort*)alloc(8192L * 1824 / 2);
    ushort* h1b    = (ushort*)alloc(8192L * 512 / 2);
    ushort* wc1b   = (ushort*)alloc(512L * 1824 / 2);
    ushort* wc2b   = (ushort*)alloc(512L * 512 / 2);
    ushort* w1tb   = (ushort*)alloc(1024L * 128 / 2);
    ushort* w2tb   = (ushort*)alloc(2048L * 128 / 2);
    ushort* w3tb   = (ushort*)alloc(2048L * 256 / 2);
    ushort* w4tb   = (ushort*)alloc(4096L * 256 / 2);
    ushort* fm0b   = (ushort*)alloc(8192L * 128 / 2);
    ushort* fp1b   = (ushort*)alloc(2048L * 128 / 2);
    ushort* fm2b   = (ushort*)alloc(2048L * 256 / 2);
    ushort* fp2b   = (ushort*)alloc(512L * 256 / 2);

    auto nblk = [](long n, int b) { return (unsigned)((n + b - 1) / b); };

    hipMemsetAsync(statbase, 0, 3328 * sizeof(float), stream);
    prep_uber<<<nblk(PB3, 256), 256, 0, stream>>>(dir0, dir1, dir2, dir3, dir4,
                                                  sd0, sd1, sd2, sd3, sd4,
                                                  wc3, wc3t, wc1, wc1b, wc2, wc2b);
    wt_trans_all<<<1920, 256, 0, stream>>>(w1, w2, w3, w4, w1tb, w2tb, w3tb, w4tb);

    knn_part_uber<<<756, 256, 0, stream>>>(verts, pd, pi, n1, n2);
    knn_merge_uber<<<52, 256, 0, stream>>>(pd, pi, nb, nb1, nb2, nbp1, nbp2);

    conv_surface_kernel<<<BSZ * 2048, 128, 0, stream>>>(verts, nb, sd0, fm0, fm0b);

    // layer1 (M=8192, N=1024, K=128)
    gemm_mfma_bt_kernel<<<dim3(8, 64), 256, 0, stream>>>(fm0b, w1tb, b1, fbuf, nullptr, 8192, 1024, 128, 0);
    conv_act_kernel<<<BSZ * 2048, 128, 0, stream>>>(verts, nb, sd1, fbuf, c1, nullptr, 2048, 128);
    bn_stat_kernel<<<256, 256, 0, stream>>>(c1, stat1, 8192, 128);
    bn_apply_relu_kernel<<<nblk(8192L * 128, 256), 256, 0, stream>>>(c1, stat1, g_bn1, be_bn1, fm1, nullptr, 8192, 128);

    pool_b_kernel<<<nblk(BSZ * 512L * 128, 256), 256, 0, stream>>>(fm1, nbp1, fp1b, 2048, 512, 128);

    // layer2 (M=2048, N=2048, K=128)
    gemm_mfma_bt64_kernel<<<dim3(16, 32), 256, 0, stream>>>(fp1b, w2tb, b2, fbuf, nullptr, 2048, 2048, 128, 0);
    conv_act_kernel<<<BSZ * 512, 256, 0, stream>>>(verts, nb1, sd2, fbuf, c2, nullptr, 512, 256);
    bn_stat_kernel<<<256, 256, 0, stream>>>(c2, stat2, 2048, 256);
    bn_apply_relu_kernel<<<nblk(2048L * 256, 256), 256, 0, stream>>>(c2, stat2, g_bn2, be_bn2, fm2, fm2b, 2048, 256);

    // layer3 (M=2048, N=2048, K=256)
    gemm_mfma_bt64_kernel<<<dim3(16, 32), 256, 0, stream>>>(fm2b, w3tb, b3, fbuf, nullptr, 2048, 2048, 256, 0);
    conv_act_kernel<<<BSZ * 512, 256, 0, stream>>>(verts, nb1, sd3, fbuf, c3, nullptr, 512, 256);
    bn_stat_kernel<<<256, 256, 0, stream>>>(c3, stat3, 2048, 256);
    bn_apply_relu_kernel<<<nblk(2048L * 256, 256), 256, 0, stream>>>(c3, stat3, g_bn3, be_bn3, fm3, nullptr, 2048, 256);

    pool_b_kernel<<<nblk(BSZ * 128L * 256, 256), 256, 0, stream>>>(fm3, nbp2, fp2b, 512, 128, 256);

    // layer4 (M=512, N=4096, K=256)
    gemm_mfma_bt64_kernel<<<dim3(32, 8), 256, 0, stream>>>(fp2b, w4tb, b4, fbuf, nullptr, 512, 4096, 256, 0);
    conv_act_kernel<<<BSZ * 128, 512, 0, stream>>>(verts, nb2, sd4, fbuf, fm4, fg_enc, 128, 512);

    // fuse -> bf16 GEMM input + fp32 feat (direct to d_out)
    fuse_bf_kernel<<<8192, 256, 0, stream>>>(fm0, fm1, fm2, fm3, fm4, fg_enc, onehot,
                                             n1, n2, fuse_b, outf + 245760);

    // MLP head
    gemm_mfma_bt64_kernel<<<dim3(4, 128), 256, 0, stream>>>(fuse_b, wc1b, bc1, nullptr, h1b, 8192, 512, 1824, 1);
    gemm_mfma_bt64_kernel<<<dim3(4, 128), 256, 0, stream>>>(h1b, wc2b, bc2, h2, nullptr, 8192, 512, 512, 1);
    wc3_kernel<<<1024, 256, 0, stream>>>(h2, wc3t, bc3, outf);
}

// Round 10
// 489.529 us; speedup vs baseline: 1.0426x; 1.0426x over previous
//
#include <hip/hip_runtime.h>
#include <hip/hip_bf16.h>
#include <math.h>

#define BSZ 4
#define VN 2048
#define SS 7
#define KNB 10

typedef __attribute__((ext_vector_type(8))) short short8;
typedef __attribute__((ext_vector_type(4))) float f32x4;
typedef __attribute__((address_space(1))) const void gcvoid;
typedef __attribute__((address_space(3))) void lvoid;

__device__ inline ushort f2bf(float x) {
    __hip_bfloat16 h = __float2bfloat16(x);
    return *(ushort*)&h;
}

__device__ inline void gl2lds16(const ushort* g, ushort* l) {
    __builtin_amdgcn_global_load_lds((gcvoid*)g, (lvoid*)l, 16, 0, 0);
}

__device__ inline unsigned fenc(float f) {
    unsigned b = __float_as_uint(f);
    return (b & 0x80000000u) ? ~b : (b | 0x80000000u);
}
__device__ inline float fdec(unsigned e) {
    unsigned b = (e & 0x80000000u) ? (e & 0x7FFFFFFFu) : ~e;
    return __uint_as_float(b);
}

#define INS(dq, iq, dd, jj) { bool lt_ = (dd) < (dq); \
    float dmn_ = lt_ ? (dd) : (dq); float dmx_ = lt_ ? (dq) : (dd); \
    int imn_ = lt_ ? (jj) : (iq); int imx_ = lt_ ? (iq) : (jj); \
    (dq) = dmn_; (iq) = imn_; (dd) = dmx_; (jj) = imx_; }

// ---------------------------------------------------------------- prep uber
#define PB0 8960L
#define PB1 24320L
#define PB2 958208L
#define PB3 1220352L

__global__ void prep_uber(const float* __restrict__ d0, const float* __restrict__ d1,
                          const float* __restrict__ d2, const float* __restrict__ d3,
                          const float* __restrict__ d4,
                          float* __restrict__ s0, float* __restrict__ s1,
                          float* __restrict__ s2, float* __restrict__ s3, float* __restrict__ s4,
                          const float* __restrict__ wc3, float* __restrict__ wc3t,
                          const float* __restrict__ wc1, ushort* __restrict__ wc1b,
                          const float* __restrict__ wc2, ushort* __restrict__ wc2b) {
    long i = blockIdx.x * 256L + threadIdx.x;
    if (i < PB0) {
        const float* src; float* dst; int C, c;
        if (i < 896)        { src = d0; dst = s0; C = 896;  c = (int)i; }
        else if (i < 1792)  { src = d1; dst = s1; C = 896;  c = (int)i - 896; }
        else if (i < 3584)  { src = d2; dst = s2; C = 1792; c = (int)i - 1792; }
        else if (i < 5376)  { src = d3; dst = s3; C = 1792; c = (int)i - 3584; }
        else                { src = d4; dst = s4; C = 3584; c = (int)i - 5376; }
        float a = src[c], b = src[C + c], e = src[2 * C + c];
        float den = fmaxf(sqrtf(a * a + b * b + e * e), 1e-12f);
        dst[c] = a / den; dst[C + c] = b / den; dst[2 * C + c] = e / den;
    } else if (i < PB1) {
        long j = i - PB0;
        int o = (int)(j / 512), k = (int)(j % 512);
        wc3t[(long)k * 30 + o] = wc3[j];
    } else if (i < PB2) {
        long j = i - PB1;
        int c = (int)(j % 1824);
        long r = j / 1824;
        wc1b[j] = f2bf(c < 1808 ? wc1[r * 1808 + c] : 0.f);
    } else if (i < PB3) {
        long j = i - PB2;
        wc2b[j] = f2bf(wc2[j]);
    }
}

// ---------------------------------------------------------------- layer weights tiled transpose
__global__ __launch_bounds__(256) void wt_trans_all(const float* __restrict__ w1, const float* __restrict__ w2,
                                                    const float* __restrict__ w3, const float* __restrict__ w4,
                                                    ushort* __restrict__ o1, ushort* __restrict__ o2,
                                                    ushort* __restrict__ o3, ushort* __restrict__ o4) {
    __shared__ float tile[32][33];
    int gb = blockIdx.x;
    const float* w; ushort* o; int K, N, t;
    if (gb < 128)      { w = w1; o = o1; K = 128; N = 1024; t = gb; }
    else if (gb < 384) { w = w2; o = o2; K = 128; N = 2048; t = gb - 128; }
    else if (gb < 896) { w = w3; o = o3; K = 256; N = 2048; t = gb - 384; }
    else               { w = w4; o = o4; K = 256; N = 4096; t = gb - 896; }
    int tn = t % (N / 32), tk = t / (N / 32);
    int n0 = tn * 32, k0 = tk * 32;
    int tx = threadIdx.x % 32, ty = threadIdx.x / 32;
#pragma unroll
    for (int r = 0; r < 32; r += 8)
        tile[ty + r][tx] = w[(long)(k0 + ty + r) * N + n0 + tx];
    __syncthreads();
#pragma unroll
    for (int r = 0; r < 32; r += 8)
        o[(long)(n0 + ty + r) * K + k0 + tx] = f2bf(tile[tx][ty + r]);
}

// ---------------------------------------------------------------- knn uber (dual-list part, hierarchical merge)
#define KOFF0 0L
#define KOFF1 2621440L
#define KOFF2 2785280L
#define KOFF3 2795520L
#define KOFF4 3057664L
#define KTOT  3074048L

template <int KK>
__device__ void knn_part_dev(const float* __restrict__ verts, int Nsrc, int T, int nch,
                             int tile, int b, int ch,
                             float* __restrict__ pd, int* __restrict__ pi,
                             float4* __restrict__ s4) {
    const float* vb = verts + (long)b * VN * 3;
    int j0 = ch * 128;
    for (int j = threadIdx.x; j < 128; j += 256) {
        float x = vb[(j0 + j) * 3 + 0];
        float y = vb[(j0 + j) * 3 + 1];
        float z = vb[(j0 + j) * 3 + 2];
        s4[j] = make_float4(x, y, z, x * x + y * y + z * z);
    }
    __syncthreads();
    int i = tile * 256 + threadIdx.x;
    if (i >= T) return;
    float px = vb[i * 3], py = vb[i * 3 + 1], pz = vb[i * 3 + 2];
    float d0[KK], d1[KK]; int id0[KK], id1[KK];
#pragma unroll
    for (int q = 0; q < KK; q++) { d0[q] = 1e30f; id0[q] = 0; d1[q] = 1e30f; id1[q] = 0; }
    for (int j = 0; j < 64; j++) {
        float4 sA = s4[j];
        float4 sB = s4[64 + j];
        float dA = fmaf(-2.f, px * sA.x + py * sA.y + pz * sA.z, sA.w);
        float dB = fmaf(-2.f, px * sB.x + py * sB.y + pz * sB.z, sB.w);
        int jA = j0 + j, jB = j0 + 64 + j;
        dA = (jA == i) ? 1e30f : dA;
        dB = (jB == i) ? 1e30f : dB;
#pragma unroll
        for (int q = 0; q < KK; q++) { INS(d0[q], id0[q], dA, jA); }
#pragma unroll
        for (int q = 0; q < KK; q++) { INS(d1[q], id1[q], dB, jB); }
    }
    long base = (((long)b * T + i) * nch * 2 + 2 * ch) * KK;
#pragma unroll
    for (int q = 0; q < KK; q++) { pd[base + q] = d0[q]; pi[base + q] = id0[q]; }
#pragma unroll
    for (int q = 0; q < KK; q++) { pd[base + KK + q] = d1[q]; pi[base + KK + q] = id1[q]; }
}

__device__ void nearest_dev(const float* __restrict__ verts, int SN, int* __restrict__ out,
                            int gl, float4* __restrict__ s4) {
    int t = gl * 256 + threadIdx.x;
    int b = t / VN;
    const float* vb = verts + (long)b * VN * 3;
    for (int j = threadIdx.x; j < SN; j += 256) {
        float x = vb[j * 3], y = vb[j * 3 + 1], z = vb[j * 3 + 2];
        s4[j] = make_float4(x, y, z, x * x + y * y + z * z);
    }
    __syncthreads();
    int i = t % VN;
    float px = vb[i * 3], py = vb[i * 3 + 1], pz = vb[i * 3 + 2];
    int h = SN / 2;
    float b0 = 1e30f, b1 = 1e30f; int i0 = 0, i1 = 0;
    for (int j = 0; j < h; j++) {
        float4 sA = s4[j];
        float4 sB = s4[h + j];
        float dA = fmaf(-2.f, px * sA.x + py * sA.y + pz * sA.z, sA.w);
        float dB = fmaf(-2.f, px * sB.x + py * sB.y + pz * sB.z, sB.w);
        bool lA = dA < b0; b0 = lA ? dA : b0; i0 = lA ? j : i0;
        bool lB = dB < b1; b1 = lB ? dB : b1; i1 = lB ? (h + j) : i1;
    }
    out[t] = (b1 < b0) ? i1 : i0;
}

__global__ __launch_bounds__(256) void knn_part_uber(const float* __restrict__ verts,
                                                     float* __restrict__ pd, int* __restrict__ pi,
                                                     int* __restrict__ n1, int* __restrict__ n2) {
    __shared__ float4 smem[512];
    int gb = blockIdx.x;
    if (gb < 512) {
        int tile = gb % 8, bc = gb / 8;
        knn_part_dev<10>(verts, 2048, 2048, 16, tile, bc / 16, bc % 16, pd + KOFF0, pi + KOFF0, smem);
    } else if (gb < 544) {
        int local = gb - 512, tile = local % 2, bc = local / 2;
        knn_part_dev<10>(verts, 512, 512, 4, tile, bc / 4, bc % 4, pd + KOFF1, pi + KOFF1, smem);
    } else if (gb < 548) {
        int bc = gb - 544;
        knn_part_dev<10>(verts, 128, 128, 1, 0, bc, 0, pd + KOFF2, pi + KOFF2, smem);
    } else if (gb < 676) {
        int local = gb - 548, tile = local % 2, bc = local / 2;
        knn_part_dev<4>(verts, 2048, 512, 16, tile, bc / 16, bc % 16, pd + KOFF3, pi + KOFF3, smem);
    } else if (gb < 692) {
        int bc = gb - 676;
        knn_part_dev<4>(verts, 512, 128, 4, 0, bc / 4, bc % 4, pd + KOFF4, pi + KOFF4, smem);
    } else if (gb < 724) {
        nearest_dev(verts, 512, n1, gb - 692, smem);
    } else {
        nearest_dev(verts, 128, n2, gb - 724, smem);
    }
}

// hierarchical merge: 4 threads/target (stage A: NCH/4 chunks each -> LDS), sub0 merges 4 lists (stage B)
template <int KK, int NCH>
__device__ void knn_merge2_dev(const float* __restrict__ pd, const int* __restrict__ pi,
                               int blk, int* __restrict__ out, float* sdl, int* sil) {
    int tgt = threadIdx.x >> 2;     // 0..63
    int sub = threadIdx.x & 3;      // 0..3
    long t = (long)blk * 64 + tgt;
    constexpr int GRP = (NCH + 3) / 4;
    float d[KK]; int id[KK];
#pragma unroll
    for (int q = 0; q < KK; q++) { d[q] = 1e30f; id[q] = 0; }
    int c0 = sub * GRP;
    int c1 = (c0 + GRP < NCH) ? c0 + GRP : NCH;
    for (int c = c0; c < c1; c++) {
        long base = (t * NCH + c) * KK;
        for (int q = 0; q < KK; q++) {
            float dd = pd[base + q];
            if (dd >= d[KK - 1]) break;     // partial lists sorted ascending
            int jj = pi[base + q];
#pragma unroll
            for (int p = 0; p < KK; p++) { INS(d[p], id[p], dd, jj); }
        }
    }
    float* md = sdl + (long)(tgt * 4 + sub) * KK;
    int* mi = sil + (long)(tgt * 4 + sub) * KK;
#pragma unroll
    for (int q = 0; q < KK; q++) { md[q] = d[q]; mi[q] = id[q]; }
    __syncthreads();
    if (sub == 0) {
        for (int s = 1; s < 4; s++) {
            const float* od = sdl + (long)(tgt * 4 + s) * KK;
            const int* oi = sil + (long)(tgt * 4 + s) * KK;
            for (int q = 0; q < KK; q++) {
                float dd = od[q];
                if (dd >= d[KK - 1]) break;
                int jj = oi[q];
#pragma unroll
                for (int p = 0; p < KK; p++) { INS(d[p], id[p], dd, jj); }
            }
        }
#pragma unroll
        for (int q = 0; q < KK; q++) out[t * KK + q] = id[q];
    }
}

__global__ __launch_bounds__(256) void knn_merge_uber(const float* __restrict__ pd, const int* __restrict__ pi,
                                                      int* __restrict__ nb, int* __restrict__ nb1,
                                                      int* __restrict__ nb2, int* __restrict__ nbp1,
                                                      int* __restrict__ nbp2) {
    __shared__ float sdl[64 * 4 * 10];
    __shared__ int   sil[64 * 4 * 10];
    int gb = blockIdx.x;
    if (gb < 128)      knn_merge2_dev<10, 32>(pd + KOFF0, pi + KOFF0, gb, nb, sdl, sil);
    else if (gb < 160) knn_merge2_dev<10, 8>(pd + KOFF1, pi + KOFF1, gb - 128, nb1, sdl, sil);
    else if (gb < 168) knn_merge2_dev<10, 2>(pd + KOFF2, pi + KOFF2, gb - 160, nb2, sdl, sil);
    else if (gb < 200) knn_merge2_dev<4, 32>(pd + KOFF3, pi + KOFF3, gb - 168, nbp1, sdl, sil);
    else               knn_merge2_dev<4, 8>(pd + KOFF4, pi + KOFF4, gb - 200, nbp2, sdl, sil);
}

// ---------------------------------------------------------------- conv_surface (fp32 + bf16 out)
__global__ void conv_surface_kernel(const float* __restrict__ verts, const int* __restrict__ nb,
                                    const float* __restrict__ sd, float* __restrict__ fm0,
                                    ushort* __restrict__ fm0b) {
    int bv = blockIdx.x;
    int b = bv / VN, v = bv % VN;
    __shared__ float snd[KNB][3];
    int tid = threadIdx.x;
    if (tid < KNB) {
        int nj = nb[(long)bv * KNB + tid];
        const float* vb = verts + (long)b * VN * 3;
        float dx = vb[nj * 3] - vb[v * 3];
        float dy = vb[nj * 3 + 1] - vb[v * 3 + 1];
        float dz = vb[nj * 3 + 2] - vb[v * 3 + 2];
        float den = fmaxf(sqrtf(dx * dx + dy * dy + dz * dz), 1e-12f);
        snd[tid][0] = dx / den; snd[tid][1] = dy / den; snd[tid][2] = dz / den;
    }
    __syncthreads();
    int c = tid;
    float acc = 0.f;
    for (int s = 0; s < SS; s++) {
        int col = s * 128 + c;
        float s0 = sd[col], s1 = sd[896 + col], s2 = sd[2 * 896 + col];
        float m = 0.f;
#pragma unroll
        for (int n = 0; n < KNB; n++) {
            float dot = snd[n][0] * s0 + snd[n][1] * s1 + snd[n][2] * s2;
            m = fmaxf(m, dot);
        }
        acc += m;
    }
    fm0[(long)bv * 128 + c] = acc;
    fm0b[(long)bv * 128 + c] = f2bf(acc);
}

// ---------------------------------------------------------------- conv_layer act (+opt fg max)
__global__ void conv_act_kernel(const float* __restrict__ verts, const int* __restrict__ nb,
                                const float* __restrict__ sd, const float* __restrict__ fo,
                                float* __restrict__ out, unsigned* __restrict__ fgmax,
                                int Vl, int outC) {
    int bv = blockIdx.x;
    int b = bv / Vl, v = bv % Vl;
    __shared__ float snd[KNB][3];
    __shared__ int srow[KNB];
    int tid = threadIdx.x;
    if (tid < KNB) {
        int nj = nb[(long)bv * KNB + tid];
        srow[tid] = b * Vl + nj;
        const float* vb = verts + (long)b * VN * 3;
        float dx = vb[nj * 3] - vb[v * 3];
        float dy = vb[nj * 3 + 1] - vb[v * 3 + 1];
        float dz = vb[nj * 3 + 2] - vb[v * 3 + 2];
        float den = fmaxf(sqrtf(dx * dx + dy * dy + dz * dz), 1e-12f);
        snd[tid][0] = dx / den; snd[tid][1] = dy / den; snd[tid][2] = dz / den;
    }
    __syncthreads();
    int c = tid;
    int SC = SS * outC;
    int foN = SC + outC;
    float acc = fo[(long)bv * foN + c];
    for (int s = 0; s < SS; s++) {
        int col = s * outC + c;
        float s0 = sd[col], s1 = sd[SC + col], s2 = sd[2 * SC + col];
        float m = -1e30f;
#pragma unroll
        for (int n = 0; n < KNB; n++) {
            float dot = snd[n][0] * s0 + snd[n][1] * s1 + snd[n][2] * s2;
            float th = fmaxf(dot, 0.f);
            float sup = fo[(long)srow[n] * foN + outC + col];
            m = fmaxf(m, th * sup);
        }
        acc += m;
    }
    out[(long)bv * outC + c] = acc;
    if (fgmax) atomicMax(&fgmax[b * outC + c], fenc(acc));
}

// ---------------------------------------------------------------- batchnorm stats
__global__ __launch_bounds__(256) void bn_stat_kernel(const float* __restrict__ x,
                                                      float* __restrict__ stat, int R, int C) {
    int rp = 256 / C;
    int c = threadIdx.x % C;
    int rs = threadIdx.x / C;
    float s = 0.f, s2 = 0.f;
    for (long r = (long)blockIdx.x * rp + rs; r < R; r += (long)gridDim.x * rp) {
        float v = x[r * C + c];
        s += v; s2 += v * v;
    }
    atomicAdd(&stat[c], s);
    atomicAdd(&stat[C + c], s2);
}

__global__ void bn_apply_relu_kernel(const float* __restrict__ x, const float* __restrict__ stat,
                                     const float* __restrict__ g, const float* __restrict__ be,
                                     float* __restrict__ out, ushort* __restrict__ outb, int R, int C) {
    long i = blockIdx.x * 256L + threadIdx.x;
    if (i >= (long)R * C) return;
    int c = (int)(i % C);
    float mu = stat[c] / R;
    float var = stat[C + c] / R - mu * mu;
    var = fmaxf(var, 0.f);
    float y = (x[i] - mu) * rsqrtf(var + 1e-5f) * g[c] + be[c];
    y = fmaxf(y, 0.f);
    out[i] = y;
    if (outb) outb[i] = f2bf(y);
}

// ---------------------------------------------------------------- pool -> bf16
__global__ void pool_b_kernel(const float* __restrict__ fm, const int* __restrict__ idx,
                              ushort* __restrict__ out, int Vin, int T, int C) {
    long i = blockIdx.x * 256L + threadIdx.x;
    if (i >= (long)BSZ * T * C) return;
    int c = (int)(i % C);
    long bt = i / C;
    int b = (int)(bt / T), t = (int)(bt % T);
    const int* id = idx + ((long)b * T + t) * 4;
    float m = -1e30f;
#pragma unroll
    for (int n = 0; n < 4; n++)
        m = fmaxf(m, fm[((long)b * Vin + id[n]) * C + c]);
    out[i] = f2bf(m);
}

// ---------------------------------------------------------------- bf16 MFMA GEMM, 128x128 tile (async LDS)
__global__ __launch_bounds__(256) void gemm_mfma_bt_kernel(
    const ushort* __restrict__ A, const ushort* __restrict__ Bt,
    const float* __restrict__ bias, float* __restrict__ Cf, ushort* __restrict__ Cb,
    int M, int N, int K, int relu)
{
    __shared__ ushort As[128 * 32];
    __shared__ ushort Bs[128 * 32];
    int t = threadIdx.x;
    int w = t >> 6, l = t & 63;
    int quad = l >> 4, lm = l & 15;
    int wm = w >> 1, wn = w & 1;
    long m0 = blockIdx.y * 128L;
    long n0 = blockIdx.x * 128L;
    int lr = t >> 2;
    int lk = (t & 3) * 8;
    f32x4 acc[4][4];
#pragma unroll
    for (int i = 0; i < 4; i++)
#pragma unroll
        for (int j = 0; j < 4; j++) acc[i][j] = (f32x4){0.f, 0.f, 0.f, 0.f};

    for (int k0 = 0; k0 < K; k0 += 32) {
        __syncthreads();
        gl2lds16(A + (m0 + lr) * K + k0 + lk, &As[lr * 32 + lk]);
        gl2lds16(A + (m0 + 64 + lr) * K + k0 + lk, &As[(64 + lr) * 32 + lk]);
        gl2lds16(Bt + (n0 + lr) * K + k0 + lk, &Bs[lr * 32 + lk]);
        gl2lds16(Bt + (n0 + 64 + lr) * K + k0 + lk, &Bs[(64 + lr) * 32 + lk]);
        __syncthreads();
        short8 af[4], bfr[4];
#pragma unroll
        for (int i = 0; i < 4; i++)
            af[i] = *(const short8*)&As[(wm * 64 + i * 16 + lm) * 32 + quad * 8];
#pragma unroll
        for (int j = 0; j < 4; j++)
            bfr[j] = *(const short8*)&Bs[(wn * 64 + j * 16 + lm) * 32 + quad * 8];
#pragma unroll
        for (int i = 0; i < 4; i++)
#pragma unroll
            for (int j = 0; j < 4; j++)
                acc[i][j] = __builtin_amdgcn_mfma_f32_16x16x32_bf16(af[i], bfr[j], acc[i][j], 0, 0, 0);
    }
#pragma unroll
    for (int i = 0; i < 4; i++) {
#pragma unroll
        for (int j = 0; j < 4; j++) {
            int n = (int)n0 + wn * 64 + j * 16 + lm;
            float bv = bias[n];
#pragma unroll
            for (int r = 0; r < 4; r++) {
                int m = (int)m0 + wm * 64 + i * 16 + quad * 4 + r;
                float v = acc[i][j][r] + bv;
                if (relu) v = fmaxf(v, 0.f);
                if (Cf) Cf[(long)m * N + n] = v;
                if (Cb) Cb[(long)m * N + n] = f2bf(v);
            }
        }
    }
}

// ---------------------------------------------------------------- bf16 MFMA GEMM, 64x128 tile (async LDS)
__global__ __launch_bounds__(256) void gemm_mfma_bt64_kernel(
    const ushort* __restrict__ A, const ushort* __restrict__ Bt,
    const float* __restrict__ bias, float* __restrict__ Cf, ushort* __restrict__ Cb,
    int M, int N, int K, int relu)
{
    __shared__ ushort As[64 * 32];
    __shared__ ushort Bs[128 * 32];
    int t = threadIdx.x;
    int w = t >> 6, l = t & 63;
    int quad = l >> 4, lm = l & 15;
    int wm = w >> 1, wn = w & 1;
    long m0 = blockIdx.y * 64L;
    long n0 = blockIdx.x * 128L;
    int lr = t >> 2;
    int lk = (t & 3) * 8;
    f32x4 acc[2][4];
#pragma unroll
    for (int i = 0; i < 2; i++)
#pragma unroll
        for (int j = 0; j < 4; j++) acc[i][j] = (f32x4){0.f, 0.f, 0.f, 0.f};

    for (int k0 = 0; k0 < K; k0 += 32) {
        __syncthreads();
        gl2lds16(A + (m0 + lr) * K + k0 + lk, &As[lr * 32 + lk]);
        gl2lds16(Bt + (n0 + lr) * K + k0 + lk, &Bs[lr * 32 + lk]);
        gl2lds16(Bt + (n0 + 64 + lr) * K + k0 + lk, &Bs[(64 + lr) * 32 + lk]);
        __syncthreads();
        short8 af[2], bfr[4];
#pragma unroll
        for (int i = 0; i < 2; i++)
            af[i] = *(const short8*)&As[(wm * 32 + i * 16 + lm) * 32 + quad * 8];
#pragma unroll
        for (int j = 0; j < 4; j++)
            bfr[j] = *(const short8*)&Bs[(wn * 64 + j * 16 + lm) * 32 + quad * 8];
#pragma unroll
        for (int i = 0; i < 2; i++)
#pragma unroll
            for (int j = 0; j < 4; j++)
                acc[i][j] = __builtin_amdgcn_mfma_f32_16x16x32_bf16(af[i], bfr[j], acc[i][j], 0, 0, 0);
    }
#pragma unroll
    for (int i = 0; i < 2; i++) {
#pragma unroll
        for (int j = 0; j < 4; j++) {
            int n = (int)n0 + wn * 64 + j * 16 + lm;
            float bv = bias[n];
#pragma unroll
            for (int r = 0; r < 4; r++) {
                int m = (int)m0 + wm * 32 + i * 16 + quad * 4 + r;
                float v = acc[i][j][r] + bv;
                if (relu) v = fmaxf(v, 0.f);
                if (Cf) Cf[(long)m * N + n] = v;
                if (Cb) Cb[(long)m * N + n] = f2bf(v);
            }
        }
    }
}

// ---------------------------------------------------------------- wc3 head
__global__ __launch_bounds__(256) void wc3_kernel(const float* __restrict__ h2,
                                                  const float* __restrict__ wc3t,
                                                  const float* __restrict__ bc3,
                                                  float* __restrict__ out) {
    int r8 = threadIdx.x >> 5;
    int c = threadIdx.x & 31;
    long row = blockIdx.x * 8L + r8;
    const float* hr = h2 + row * 512;
    float acc = 0.f;
    if (c < 30) {
        for (int k = 0; k < 512; k++)
            acc += hr[k] * wc3t[k * 30 + c];
        acc += bc3[c];
        if (c < 6) out[row * 6 + c] = acc;
        else       out[49152 + row * 24 + (c - 6)] = acc;
    }
}

// ---------------------------------------------------------------- fuse (row-per-block)
__global__ __launch_bounds__(256) void fuse_bf_kernel(
    const float* __restrict__ fm0, const float* __restrict__ fm1,
    const float* __restrict__ fm2, const float* __restrict__ fm3,
    const float* __restrict__ fm4, const unsigned* __restrict__ fg_enc,
    const float* __restrict__ onehot,
    const int* __restrict__ n1, const int* __restrict__ n2,
    ushort* __restrict__ fuse_b, float* __restrict__ feat) {
    long row = blockIdx.x;
    int b = (int)(row >> 11);
    int i1 = n1[row], i2 = n2[row];
    const float* p0 = fm0 + row * 128;
    const float* p1 = fm1 + row * 128;
    const float* p2 = fm2 + ((long)b * 512 + i1) * 256;
    const float* p3 = fm3 + ((long)b * 512 + i1) * 256;
    const float* p4 = fm4 + ((long)b * 128 + i2) * 512;
    const unsigned* pg = fg_enc + b * 512;
    const float* po = onehot + b * 16;
    ushort* fb = fuse_b + row * 1824;
    float* ft = feat + row * 1296;
#pragma unroll
    for (int k = 0; k < 8; k++) {
        int c = threadIdx.x + k * 256;
        if (c >= 1824) break;
        float val = 0.f;
        if (c < 128)       val = p0[c];
        else if (c < 256)  val = p1[c - 128];
        else if (c < 512)  val = p2[c - 256];
        else if (c < 768)  val = p3[c - 512];
        else if (c < 1280) val = p4[c - 768];
        else if (c < 1792) val = fdec(pg[c - 1280]);
        else if (c < 1808) val = po[c - 1792];
        fb[c] = f2bf(val);
        if (c < 1280)                   ft[c] = val;
        else if (c >= 1792 && c < 1808) ft[c - 512] = val;
    }
}

// ---------------------------------------------------------------- launch

extern "C" void kernel_launch(void* const* d_in, const int* in_sizes, int n_in,
                              void* d_out, int out_size, void* d_ws, size_t ws_size,
                              hipStream_t stream) {
    const float* verts  = (const float*)d_in[0];
    const float* onehot = (const float*)d_in[1];
    const float* dir0 = (const float*)d_in[2];
    const float* w1 = (const float*)d_in[3];
    const float* b1 = (const float*)d_in[4];
    const float* dir1 = (const float*)d_in[5];
    const float* w2 = (const float*)d_in[6];
    const float* b2 = (const float*)d_in[7];
    const float* dir2 = (const float*)d_in[8];
    const float* w3 = (const float*)d_in[9];
    const float* b3 = (const float*)d_in[10];
    const float* dir3 = (const float*)d_in[11];
    const float* w4 = (const float*)d_in[12];
    const float* b4 = (const float*)d_in[13];
    const float* dir4 = (const float*)d_in[14];
    const float* g_bn1 = (const float*)d_in[15];
    const float* be_bn1 = (const float*)d_in[16];
    const float* g_bn2 = (const float*)d_in[17];
    const float* be_bn2 = (const float*)d_in[18];
    const float* g_bn3 = (const float*)d_in[19];
    const float* be_bn3 = (const float*)d_in[20];
    const float* wc1 = (const float*)d_in[21];
    const float* bc1 = (const float*)d_in[22];
    const float* wc2 = (const float*)d_in[23];
    const float* bc2 = (const float*)d_in[24];
    const float* wc3 = (const float*)d_in[25];
    const float* bc3 = (const float*)d_in[26];
    float* outf = (float*)d_out;

    float* wsf = (float*)d_ws;
    size_t off = 0;
    auto alloc = [&](size_t n) { float* p = wsf + off; off += (n + 15) & ~(size_t)15; return p; };

    float* sd0 = alloc(3 * 896);
    float* sd1 = alloc(3 * 896);
    float* sd2 = alloc(3 * 1792);
    float* sd3 = alloc(3 * 1792);
    float* sd4 = alloc(3 * 3584);
    float* wc3t = alloc(512L * 30);
    float* fm0 = alloc(8192L * 128);
    float* fm1 = alloc(8192L * 128);
    float* c1  = alloc(8192L * 128);
    float* fm2 = alloc(2048L * 256);
    float* c2  = alloc(2048L * 256);
    float* fm3 = alloc(2048L * 256);
    float* c3  = alloc(2048L * 256);
    float* fm4 = alloc(512L * 512);
    float* statbase = alloc(3328);
    float* stat1 = statbase;
    float* stat2 = statbase + 256;
    float* stat3 = statbase + 768;
    unsigned* fg_enc = (unsigned*)(statbase + 1280);
    float* fbuf = alloc(8192L * 1024);
    float* h2 = alloc(8192L * 512);
    float* pd  = alloc(KTOT);
    int* pi    = (int*)alloc(KTOT);
    int* nb   = (int*)alloc(8192L * KNB);
    int* nb1  = (int*)alloc(2048L * KNB);
    int* nb2  = (int*)alloc(512L * KNB);
    int* nbp1 = (int*)alloc(2048L * 4);
    int* nbp2 = (int*)alloc(512L * 4);
    int* n1   = (int*)alloc(8192);
    int* n2   = (int*)alloc(8192);
    ushort* fuse_b = (ushort*)alloc(8192L * 1824 / 2);
    ushort* h1b    = (ushort*)alloc(8192L * 512 / 2);
    ushort* wc1b   = (ushort*)alloc(512L * 1824 / 2);
    ushort* wc2b   = (ushort*)alloc(512L * 512 / 2);
    ushort* w1tb   = (ushort*)alloc(1024L * 128 / 2);
    ushort* w2tb   = (ushort*)alloc(2048L * 128 / 2);
    ushort* w3tb   = (ushort*)alloc(2048L * 256 / 2);
    ushort* w4tb   = (ushort*)alloc(4096L * 256 / 2);
    ushort* fm0b   = (ushort*)alloc(8192L * 128 / 2);
    ushort* fp1b   = (ushort*)alloc(2048L * 128 / 2);
    ushort* fm2b   = (ushort*)alloc(2048L * 256 / 2);
    ushort* fp2b   = (ushort*)alloc(512L * 256 / 2);

    auto nblk = [](long n, int b) { return (unsigned)((n + b - 1) / b); };

    hipMemsetAsync(statbase, 0, 3328 * sizeof(float), stream);
    prep_uber<<<nblk(PB3, 256), 256, 0, stream>>>(dir0, dir1, dir2, dir3, dir4,
                                                  sd0, sd1, sd2, sd3, sd4,
                                                  wc3, wc3t, wc1, wc1b, wc2, wc2b);
    wt_trans_all<<<1920, 256, 0, stream>>>(w1, w2, w3, w4, w1tb, w2tb, w3tb, w4tb);

    knn_part_uber<<<756, 256, 0, stream>>>(verts, pd, pi, n1, n2);
    knn_merge_uber<<<208, 256, 0, stream>>>(pd, pi, nb, nb1, nb2, nbp1, nbp2);

    conv_surface_kernel<<<BSZ * 2048, 128, 0, stream>>>(verts, nb, sd0, fm0, fm0b);

    // layer1 (M=8192, N=1024, K=128)
    gemm_mfma_bt_kernel<<<dim3(8, 64), 256, 0, stream>>>(fm0b, w1tb, b1, fbuf, nullptr, 8192, 1024, 128, 0);
    conv_act_kernel<<<BSZ * 2048, 128, 0, stream>>>(verts, nb, sd1, fbuf, c1, nullptr, 2048, 128);
    bn_stat_kernel<<<256, 256, 0, stream>>>(c1, stat1, 8192, 128);
    bn_apply_relu_kernel<<<nblk(8192L * 128, 256), 256, 0, stream>>>(c1, stat1, g_bn1, be_bn1, fm1, nullptr, 8192, 128);

    pool_b_kernel<<<nblk(BSZ * 512L * 128, 256), 256, 0, stream>>>(fm1, nbp1, fp1b, 2048, 512, 128);

    // layer2 (M=2048, N=2048, K=128)
    gemm_mfma_bt64_kernel<<<dim3(16, 32), 256, 0, stream>>>(fp1b, w2tb, b2, fbuf, nullptr, 2048, 2048, 128, 0);
    conv_act_kernel<<<BSZ * 512, 256, 0, stream>>>(verts, nb1, sd2, fbuf, c2, nullptr, 512, 256);
    bn_stat_kernel<<<256, 256, 0, stream>>>(c2, stat2, 2048, 256);
    bn_apply_relu_kernel<<<nblk(2048L * 256, 256), 256, 0, stream>>>(c2, stat2, g_bn2, be_bn2, fm2, fm2b, 2048, 256);

    // layer3 (M=2048, N=2048, K=256)
    gemm_mfma_bt64_kernel<<<dim3(16, 32), 256, 0, stream>>>(fm2b, w3tb, b3, fbuf, nullptr, 2048, 2048, 256, 0);
    conv_act_kernel<<<BSZ * 512, 256, 0, stream>>>(verts, nb1, sd3, fbuf, c3, nullptr, 512, 256);
    bn_stat_kernel<<<256, 256, 0, stream>>>(c3, stat3, 2048, 256);
    bn_apply_relu_kernel<<<nblk(2048L * 256, 256), 256, 0, stream>>>(c3, stat3, g_bn3, be_bn3, fm3, nullptr, 2048, 256);

    pool_b_kernel<<<nblk(BSZ * 128L * 256, 256), 256, 0, stream>>>(fm3, nbp2, fp2b, 512, 128, 256);

    // layer4 (M=512, N=4096, K=256)
    gemm_mfma_bt64_kernel<<<dim3(32, 8), 256, 0, stream>>>(fp2b, w4tb, b4, fbuf, nullptr, 512, 4096, 256, 0);
    conv_act_kernel<<<BSZ * 128, 512, 0, stream>>>(verts, nb2, sd4, fbuf, fm4, fg_enc, 128, 512);

    // fuse -> bf16 GEMM input + fp32 feat (direct to d_out)
    fuse_bf_kernel<<<8192, 256, 0, stream>>>(fm0, fm1, fm2, fm3, fm4, fg_enc, onehot,
                                             n1, n2, fuse_b, outf + 245760);

    // MLP head
    gemm_mfma_bt64_kernel<<<dim3(4, 128), 256, 0, stream>>>(fuse_b, wc1b, bc1, nullptr, h1b, 8192, 512, 1824, 1);
    gemm_mfma_bt64_kernel<<<dim3(4, 128), 256, 0, stream>>>(h1b, wc2b, bc2, h2, nullptr, 8192, 512, 512, 1);
    wc3_kernel<<<1024, 256, 0, stream>>>(h2, wc3t, bc3, outf);
}